// Round 2
// baseline (39.087 us; speedup 1.0000x reference)
//
#include <hip/hip_runtime.h>
#include <math.h>

#define D_IN  2048
#define D_OUT 8192

// Global LDS swizzle on float4 index: phys(q) = q ^ ((q>>3)&7).
// Applied consistently to ALL transform-phase accesses; verified conflict-free
// (each 8-lane group covers all 8 bank quads) for phases A-write, B r/w, C r/w, D read.

__global__ __launch_bounds__(256) void fastfood_kernel(
    const float* __restrict__ xg, const float* __restrict__ Bg,
    const float* __restrict__ Gg, const float* __restrict__ Sg,
    const int*   __restrict__ Pg, const float* __restrict__ Ug,
    float* __restrict__ outg)
{
  __shared__ float4 b4[D_OUT / 4];   // 32 KB single buffer
  float* b_f = reinterpret_cast<float*>(b4);

  const int t    = threadIdx.x;   // 0..255
  const int lane = t & 63;
  const int wave = t >> 6;
  const int row  = blockIdx.x;
  const int t7   = t & 7;

  // ================= FWHT-2048 of B*x =================
  // thread holds elements e = t*8 + k  (bits 0-2 = k, 3-8 = lane, 9-10 = wave)
  float a8[8];
  {
    const float4* x4 = reinterpret_cast<const float4*>(xg + (size_t)row * D_IN);
    const float4* Bp = reinterpret_cast<const float4*>(Bg);
    float4 xa = x4[2 * t], xb = x4[2 * t + 1];
    float4 ba = Bp[2 * t], bb = Bp[2 * t + 1];
    a8[0] = xa.x * ba.x; a8[1] = xa.y * ba.y; a8[2] = xa.z * ba.z; a8[3] = xa.w * ba.w;
    a8[4] = xb.x * bb.x; a8[5] = xb.y * bb.y; a8[6] = xb.z * bb.z; a8[7] = xb.w * bb.w;
  }
#pragma unroll
  for (int h = 1; h <= 4; h <<= 1)
#pragma unroll
    for (int i = 0; i < 8; ++i)
      if (!(i & h)) { float lo = a8[i], hi = a8[i | h]; a8[i] = lo + hi; a8[i | h] = lo - hi; }
#pragma unroll
  for (int m = 1; m <= 32; m <<= 1) {
    float sgn = (lane & m) ? -1.0f : 1.0f;
#pragma unroll
    for (int k = 0; k < 8; ++k) {
      float p = __shfl_xor(a8[k], m, 64);
      a8[k] = fmaf(sgn, a8[k], p);  // bit set: partner - mine ; clear: mine + partner
    }
  }
  // scratch (pre-final 2 stages), linear at float4 [0:512)
  b4[2 * t]     = make_float4(a8[0], a8[1], a8[2], a8[3]);
  b4[2 * t + 1] = make_float4(a8[4], a8[5], a8[6], a8[7]);

  // prefetch P while scratch settles
  int4 pp[8];
  {
    const int4* P4 = reinterpret_cast<const int4*>(Pg);
#pragma unroll
    for (int g = 0; g < 8; ++g) pp[g] = P4[t * 8 + g];
  }
  __syncthreads();
  // stages h=512,1024: 4-way cross-wave combine
  {
    float pw[4][8];
#pragma unroll
    for (int w2 = 0; w2 < 4; ++w2) {
      float4 v0 = b4[(w2 * 64 + lane) * 2];
      float4 v1 = b4[(w2 * 64 + lane) * 2 + 1];
      pw[w2][0] = v0.x; pw[w2][1] = v0.y; pw[w2][2] = v0.z; pw[w2][3] = v0.w;
      pw[w2][4] = v1.x; pw[w2][5] = v1.y; pw[w2][6] = v1.z; pw[w2][7] = v1.w;
    }
    float s0 = (wave & 1) ? -1.0f : 1.0f;
    float s1 = (wave & 2) ? -1.0f : 1.0f;
#pragma unroll
    for (int k = 0; k < 8; ++k) {
      float u01 = fmaf(s0, pw[1][k], pw[0][k]);   // (in0 +- in1)
      float u23 = fmaf(s0, pw[3][k], pw[2][k]);   // (in2 +- in3)
      a8[k] = fmaf(s1, u23, u01);
    }
  }
  // final a, linear at float4 [512:1024) (disjoint from scratch -> no barrier before)
  b4[512 + 2 * t]     = make_float4(a8[0], a8[1], a8[2], a8[3]);
  b4[512 + 2 * t + 1] = make_float4(a8[4], a8[5], a8[6], a8[7]);
  __syncthreads();

  // ================= gather + scale, phase A (bits 0-4) =================
  // v[k] = b[t*32 + k]
  float v[32];
  {
    const float* a_f = b_f + 2048;
    const float4* G4 = reinterpret_cast<const float4*>(Gg);
#pragma unroll
    for (int g = 0; g < 8; ++g) {
      float4 gv = G4[t * 8 + g];
      v[4 * g + 0] = a_f[pp[g].x & (D_IN - 1)] * gv.x;
      v[4 * g + 1] = a_f[pp[g].y & (D_IN - 1)] * gv.y;
      v[4 * g + 2] = a_f[pp[g].z & (D_IN - 1)] * gv.z;
      v[4 * g + 3] = a_f[pp[g].w & (D_IN - 1)] * gv.w;
    }
  }
#pragma unroll
  for (int h = 1; h <= 16; h <<= 1)
#pragma unroll
    for (int i = 0; i < 32; ++i)
      if (!(i & h)) { float lo = v[i], hi = v[i | h]; v[i] = lo + hi; v[i | h] = lo - hi; }
  __syncthreads();   // everyone's gather reads done before overwriting b
  // A-write: logical q = t*8+g -> phys = t*8 + (g^t7)
#pragma unroll
  for (int g = 0; g < 8; ++g)
    b4[t * 8 + (g ^ t7)] = make_float4(v[4 * g + 0], v[4 * g + 1], v[4 * g + 2], v[4 * g + 3]);
  __syncthreads();

  // ================= phase B (bits 5-7) =================
  // holds f = r | t7<<2 | e<<5 | (t>>3)<<8 ; logical q = t7 | e<<3 | (t>>3)<<6 ; phys = q ^ e
  float wv[32];
  {
    const int baseB = (t >> 3) << 6;
#pragma unroll
    for (int e = 0; e < 8; ++e) {
      float4 f4 = b4[baseB + (e << 3) + (t7 ^ e)];
      wv[4 * e + 0] = f4.x; wv[4 * e + 1] = f4.y; wv[4 * e + 2] = f4.z; wv[4 * e + 3] = f4.w;
    }
#pragma unroll
    for (int hb = 1; hb <= 4; hb <<= 1)    // h = 32,64,128
#pragma unroll
      for (int e = 0; e < 8; ++e)
        if (!(e & hb))
#pragma unroll
          for (int r = 0; r < 4; ++r) {
            float lo = wv[4 * e + r], hi = wv[4 * (e | hb) + r];
            wv[4 * e + r] = lo + hi; wv[4 * (e | hb) + r] = lo - hi;
          }
#pragma unroll
    for (int e = 0; e < 8; ++e)
      b4[baseB + (e << 3) + (t7 ^ e)] =
          make_float4(wv[4 * e + 0], wv[4 * e + 1], wv[4 * e + 2], wv[4 * e + 3]);
  }
  __syncthreads();

  // ================= phase C (bits 8-10) =================
  // holds f = r | t7<<2 | t37<<5 | e<<8 | (t>>6)<<11 ; phys = (t7^t37) | t37<<3 | e<<6 | (t>>6)<<9
  {
    const int t37 = (t >> 3) & 7;
    const int baseC = (t7 ^ t37) | (t37 << 3) | ((t >> 6) << 9);
#pragma unroll
    for (int e = 0; e < 8; ++e) {
      float4 f4 = b4[baseC + (e << 6)];
      wv[4 * e + 0] = f4.x; wv[4 * e + 1] = f4.y; wv[4 * e + 2] = f4.z; wv[4 * e + 3] = f4.w;
    }
#pragma unroll
    for (int hb = 1; hb <= 4; hb <<= 1)    // h = 256,512,1024
#pragma unroll
      for (int e = 0; e < 8; ++e)
        if (!(e & hb))
#pragma unroll
          for (int r = 0; r < 4; ++r) {
            float lo = wv[4 * e + r], hi = wv[4 * (e | hb) + r];
            wv[4 * e + r] = lo + hi; wv[4 * (e | hb) + r] = lo - hi;
          }
#pragma unroll
    for (int e = 0; e < 8; ++e)
      b4[baseC + (e << 6)] =
          make_float4(wv[4 * e + 0], wv[4 * e + 1], wv[4 * e + 2], wv[4 * e + 3]);
  }
  __syncthreads();

  // ================= phase D (bits 11-12) + epilogue =================
  // holds o = c<<11 | t<<3 | k  (k=0..7 contiguous) ; q = r4 | t<<1 | c<<9 ; phys low3 ^= (t>>2)&7
  {
    const int xD = (t >> 2) & 7;
    const int baseD0 = ((t >> 2) << 3) | ((((t & 3) << 1)) ^ xD);
    const int baseD1 = baseD0 ^ 1;
    float d[4][8];
#pragma unroll
    for (int c = 0; c < 4; ++c) {
      float4 lo4 = b4[baseD0 + (c << 9)];
      float4 hi4 = b4[baseD1 + (c << 9)];
      d[c][0] = lo4.x; d[c][1] = lo4.y; d[c][2] = lo4.z; d[c][3] = lo4.w;
      d[c][4] = hi4.x; d[c][5] = hi4.y; d[c][6] = hi4.z; d[c][7] = hi4.w;
    }
#pragma unroll
    for (int hb = 1; hb <= 2; hb <<= 1)    // h = 2048,4096
#pragma unroll
      for (int c = 0; c < 4; ++c)
        if (!(c & hb))
#pragma unroll
          for (int k = 0; k < 8; ++k) {
            float lo = d[c][k], hi = d[c | hb][k];
            d[c][k] = lo + hi; d[c | hb][k] = lo - hi;
          }
    const float c1 = (float)(1.0 / (6.283185307179586 * 90.50966799187809)); // 1/(2*pi*sqrt(8192))
    const float4* S4 = reinterpret_cast<const float4*>(Sg);
    const float4* U4 = reinterpret_cast<const float4*>(Ug);
    float4* out4 = reinterpret_cast<float4*>(outg + (size_t)row * D_OUT);
#pragma unroll
    for (int c = 0; c < 4; ++c)
#pragma unroll
      for (int r4 = 0; r4 < 2; ++r4) {
        int o4 = (c << 9) + 2 * t + r4;
        float4 s4 = S4[o4], u4 = U4[o4];
        float4 res;
        float rev;
        rev = fmaf(d[c][4 * r4 + 0] * s4.x, c1, u4.x); rev -= rintf(rev);
        res.x = __builtin_amdgcn_cosf(rev) * 0.015625f;
        rev = fmaf(d[c][4 * r4 + 1] * s4.y, c1, u4.y); rev -= rintf(rev);
        res.y = __builtin_amdgcn_cosf(rev) * 0.015625f;
        rev = fmaf(d[c][4 * r4 + 2] * s4.z, c1, u4.z); rev -= rintf(rev);
        res.z = __builtin_amdgcn_cosf(rev) * 0.015625f;
        rev = fmaf(d[c][4 * r4 + 3] * s4.w, c1, u4.w); rev -= rintf(rev);
        res.w = __builtin_amdgcn_cosf(rev) * 0.015625f;
        out4[o4] = res;
      }
  }
}

extern "C" void kernel_launch(void* const* d_in, const int* in_sizes, int n_in,
                              void* d_out, int out_size, void* d_ws, size_t ws_size,
                              hipStream_t stream) {
  const float* x = (const float*)d_in[0];
  const float* B = (const float*)d_in[1];
  const float* G = (const float*)d_in[2];
  const float* S = (const float*)d_in[3];
  const int*   P = (const int*)d_in[4];
  const float* U = (const float*)d_in[5];
  float* out = (float*)d_out;
  const int rows = in_sizes[0] / D_IN;  // 2048
  fastfood_kernel<<<rows, 256, 0, stream>>>(x, B, G, S, P, U, out);
}